// Round 16
// baseline (1357.229 us; speedup 1.0000x reference)
//
#include <hip/hip_runtime.h>

#define NSITES 64
#define CHI 64
#define BATCH 32768
#define LPAD 66          // L row stride in doubles

typedef double d4 __attribute__((ext_vector_type(4)));

// 32 cycles of guaranteed spacing between MFMA result writes and VALU reads,
// pinned so the compiler cannot move register-only MFMAs across (rule #18).
#define MFMA_HAZARD_FENCE() do {                                    \
    __builtin_amdgcn_sched_barrier(0);                              \
    asm volatile("s_nop 7\n\ts_nop 7\n\ts_nop 7\n\ts_nop 7" :::);   \
    __builtin_amdgcn_sched_barrier(0);                              \
} while (0)

// ============================================================================
// Kernel 1: per-site Householder QR (LAPACK dgeqrf/dorgqr convention), f64.
// UNCHANGED from round 14 (passing; 2-barrier divergence-free factor phase,
// deferred col-k scaling, zero-barrier Q-phase via Vt transpose).
// ============================================================================
__global__ __launch_bounds__(512) void qr_site_kernel(
    const float* __restrict__ W, double* __restrict__ A8)
{
    __shared__ double M[128][65];
    __shared__ double wpart[8][64];
    __shared__ double tauS[64];
    __shared__ double scS[64];
    __shared__ double redS2[8];
    __shared__ double Vt[64][136];

    const int i   = blockIdx.x;
    const int tid = threadIdx.x;

    for (int idx = tid; idx < 8192; idx += 512) {
        int l = idx >> 7, sr = idx & 127;
        M[sr][l] = (double)W[i * 8192 + idx];
    }

    const int jf = tid & 63;              // lane = column
    const int gf = tid >> 6;              // wave = row group (rows gf*16..+15)
    const int r0 = gf * 16;
    __syncthreads();

    for (int k = 0; k < 64; ++k) {
        // ---- phase A ----
        double ureg[16];
        #pragma unroll
        for (int m = 0; m < 16; ++m) {
            int rr = r0 + m;
            ureg[m] = (rr > k) ? M[rr][k] : 0.0;   // wave-broadcast reads
        }
        double np = 0.0;                  // group norm partial (all lanes, uniform)
        #pragma unroll
        for (int m = 0; m < 16; ++m) np = fma(ureg[m], ureg[m], np);
        if (jf == 0) redS2[gf] = np;
        if (jf > k) {                     // GEMV on unscaled column
            double part = 0.0;
            #pragma unroll 4
            for (int m = 0; m < 16; ++m)
                part = fma(ureg[m], M[r0 + m][jf], part);
            wpart[gf][jf] = part;
        }
        __syncthreads();                  // barrier 1

        // ---- phase B ----
        const double v2 = ((redS2[0] + redS2[1]) + (redS2[2] + redS2[3]))
                        + ((redS2[4] + redS2[5]) + (redS2[6] + redS2[7]));
        const double alpha = M[k][k];
        double beta, tk;
        if (v2 == 0.0) { beta = alpha; tk = 0.0; }
        else {
            double nrm = sqrt(alpha * alpha + v2);
            beta = (alpha >= 0.0) ? -nrm : nrm;   // LAPACK sign convention
            tk   = (beta - alpha) / beta;
        }
        const double uk   = alpha - beta;
        const double sc   = (tk != 0.0) ? (1.0 / uk) : 0.0;
        const double tau2 = (tk != 0.0) ? (tk / (uk * uk)) : 0.0;
        if (tid == 0) { tauS[k] = tk; scS[k] = sc; }
        if (jf > k) {
            const double xk = M[k][jf];   // row-k term (col k never scaled here)
            double wsum = ((wpart[0][jf] + wpart[1][jf]) + (wpart[2][jf] + wpart[3][jf]))
                        + ((wpart[4][jf] + wpart[5][jf]) + (wpart[6][jf] + wpart[7][jf]));
            const double wj = tau2 * fma(uk, xk, wsum);
            #pragma unroll 4
            for (int m = 0; m < 16; ++m) {
                int rr = r0 + m;
                M[rr][jf] = fma(-ureg[m], wj, M[rr][jf]);  // rows<=k: -0*wj, benign
            }
        }
        __syncthreads();                  // barrier 2
    }

    // one-time transpose of v's into Vt, applying the deferred scale
    for (int idx = tid; idx < 8192; idx += 512) {
        int rr = idx & 127, k = idx >> 7;
        double val = (rr > k) ? M[rr][k] * scS[k] : ((rr == k) ? 1.0 : 0.0);
        Vt[k][rr + (rr >> 4)] = val;
    }
    __syncthreads();

    // Q = H_0 ... H_63 applied to [I;0], reverse order — ZERO barriers
    const int jq = tid >> 3;
    const int qq = tid & 7;
    double E[16];
    #pragma unroll
    for (int m = 0; m < 16; ++m) E[m] = ((qq * 16 + m) == jq) ? 1.0 : 0.0;

    for (int k = 63; k >= 0; --k) {
        const double tkk = tauS[k];
        double part = 0.0;
        #pragma unroll
        for (int m = 0; m < 16; ++m) {
            int rr = qq * 16 + m;
            part = fma(Vt[k][rr + qq], E[m], part);
        }
        part += __shfl_xor(part, 1, 64);
        part += __shfl_xor(part, 2, 64);
        part += __shfl_xor(part, 4, 64);
        const double wj = tkk * part;
        #pragma unroll
        for (int m = 0; m < 16; ++m) {
            int rr = qq * 16 + m;
            E[m] = fma(-Vt[k][rr + qq], wj, E[m]);
        }
    }

    double* dst = A8 + (size_t)i * 8192 + jq * 128 + qq * 16;
    #pragma unroll
    for (int m = 0; m < 16; ++m) dst[m] = E[m];
}

// ============================================================================
// Kernel 2: sampling via f64 MFMA GEMM per site — BARRIER-FREE version.
// CHANGE vs rounds 13-15: B-fragments are read directly from A8 (L2-resident,
// 4 MiB) via global loads; the As LDS buffer, its staging, and BOTH barriers
// are eliminated. Waves are fully independent (L is wave-private LDS rows,
// same-wave program order — pattern validated r7-r15) -> natural skew lets
// other waves fill each wave's epilogue gap in the MFMA pipe.
// Block = 256 thr (4 waves, 64 batches), grid 512; LDS 33 KiB -> ~3 blocks/CU,
// ~12 waves/CU. Per-wave FMA order (kk 0..15, t 0..7) BIT-IDENTICAL to
// rounds 7-15 -> P0 and all decisions bit-identical.
// ============================================================================
#define MFMA_ROW(bp, a)                                                   \
    c0 = __builtin_amdgcn_mfma_f64_16x16x4f64((a), (bp)[  0], c0, 0,0,0); \
    c1 = __builtin_amdgcn_mfma_f64_16x16x4f64((a), (bp)[ 16], c1, 0,0,0); \
    c2 = __builtin_amdgcn_mfma_f64_16x16x4f64((a), (bp)[ 32], c2, 0,0,0); \
    c3 = __builtin_amdgcn_mfma_f64_16x16x4f64((a), (bp)[ 48], c3, 0,0,0); \
    c4 = __builtin_amdgcn_mfma_f64_16x16x4f64((a), (bp)[ 64], c4, 0,0,0); \
    c5 = __builtin_amdgcn_mfma_f64_16x16x4f64((a), (bp)[ 80], c5, 0,0,0); \
    c6 = __builtin_amdgcn_mfma_f64_16x16x4f64((a), (bp)[ 96], c6, 0,0,0); \
    c7 = __builtin_amdgcn_mfma_f64_16x16x4f64((a), (bp)[112], c7, 0,0,0);

__global__ __launch_bounds__(256, 2) void sample_kernel(
    const double* __restrict__ A8, const float* __restrict__ u,
    float* __restrict__ out)
{
    __shared__ double Lsm[64 * LPAD];     // L: [b=64][j=64 + pad], 33 KiB

    const int tid  = threadIdx.x;
    const int w    = tid >> 6;            // wave 0..3
    const int lane = tid & 63;
    const int g    = lane >> 4;           // 0..3
    const int r    = lane & 15;           // 0..15
    const int ubase = blockIdx.x * 64 + 16 * w;    // strip's first global batch

    // ---- layout probe (register-only, once) ----
    d4 zp = {0.0, 0.0, 0.0, 0.0};
    const d4 rowP = __builtin_amdgcn_mfma_f64_16x16x4f64((g == 0) ? (double)r : 0.0, 1.0, zp, 0, 0, 0);
    const d4 colP = __builtin_amdgcn_mfma_f64_16x16x4f64((g == 0) ? 1.0 : 0.0, (double)r, zp, 0, 0, 0);
    MFMA_HAZARD_FENCE();
    const int row0 = (int)(rowP.x + 0.5), row1 = (int)(rowP.y + 0.5);
    const int row2 = (int)(rowP.z + 0.5), row3 = (int)(rowP.w + 0.5);
    const int col0 = (int)(colP.x + 0.5), col1 = (int)(colP.y + 0.5);
    const int col2 = (int)(colP.z + 0.5), col3 = (int)(colP.w + 0.5);

    // init L = e_0: lane (g,r) initializes row 16w+r, cols g, g+4, ...
    // (wave-private rows; same-wave LDS program order -> no barrier ever)
    for (int j = g; j < 64; j += 4)
        Lsm[(16 * w + r) * LPAD + j] = (j == 0) ? 1.0 : 0.0;

    float* probOut = out + (size_t)BATCH * (NSITES * 2);

    for (int site = 0; site < NSITES; ++site) {
        // u values for this lane's (probed) batch rows
        const float u0 = u[(size_t)(ubase + row0) * NSITES + site];
        const float u1 = u[(size_t)(ubase + row1) * NSITES + site];
        const float u2 = u[(size_t)(ubase + row2) * NSITES + site];
        const float u3 = u[(size_t)(ubase + row3) * NSITES + site];

        d4 c0 = {0.0, 0.0, 0.0, 0.0}, c1 = c0, c2 = c0, c3 = c0;
        d4 c4 = c0, c5 = c0, c6 = c0, c7 = c0;

        const double* Lp = Lsm + (16 * w + r) * LPAD + g;      // A-op: L[16w+r][g+4kk]
        const double* Ab = A8 + (size_t)site * 8192 + g * 128 + r;  // B-op: global (L2)

        #pragma unroll
        for (int kk = 0; kk < 16; ++kk) {
            const double a = Lp[4 * kk];
            const double* bp = Ab + kk * 512;
            MFMA_ROW(bp, a)
        }
        MFMA_HAZARD_FENCE();             // settle all c-reg writes before VALU reads

        // p0 per row: tiles 0..3 are the s=0 half (col-permutation-invariant);
        // xor-butterfly over the 16-lane group (row map is r-independent).
        double P0 = fma(c3.x, c3.x, fma(c2.x, c2.x, fma(c1.x, c1.x, c0.x * c0.x)));
        double P1 = fma(c3.y, c3.y, fma(c2.y, c2.y, fma(c1.y, c1.y, c0.y * c0.y)));
        double P2 = fma(c3.z, c3.z, fma(c2.z, c2.z, fma(c1.z, c1.z, c0.z * c0.z)));
        double P3 = fma(c3.w, c3.w, fma(c2.w, c2.w, fma(c1.w, c1.w, c0.w * c0.w)));
        #pragma unroll
        for (int m = 1; m <= 8; m <<= 1) {
            P0 += __shfl_xor(P0, m, 64);
            P1 += __shfl_xor(P1, m, 64);
            P2 += __shfl_xor(P2, m, 64);
            P3 += __shfl_xor(P3, m, 64);
        }

        const bool t0 = ((double)u0 >= P0);
        const bool t1 = ((double)u1 >= P1);
        const bool t2 = ((double)u2 >= P2);
        const bool t3 = ((double)u3 >= P3);
        const double s0 = t0 ? (1.0 - P0) : P0;   // p0+p1==1 by isometry
        const double s1 = t1 ? (1.0 - P1) : P1;
        const double s2 = t2 ? (1.0 - P2) : P2;
        const double s3 = t3 ? (1.0 - P3) : P3;
        const double i0 = rsqrt(s0);              // ~1 ulp; perturbs L ~1e-15 rel
        const double i1 = rsqrt(s1);
        const double i2 = rsqrt(s2);
        const double i3 = rsqrt(s3);

        // chosen T -> new L rows at probed (row,col); wave-private rows,
        // consumed only by this wave's next-site ds_reads (program order)
        double* LwB = Lsm + (16 * w) * LPAD;
        LwB[row0 * LPAD +  0 + col0] = (t0 ? c4.x : c0.x) * i0;
        LwB[row0 * LPAD + 16 + col0] = (t0 ? c5.x : c1.x) * i0;
        LwB[row0 * LPAD + 32 + col0] = (t0 ? c6.x : c2.x) * i0;
        LwB[row0 * LPAD + 48 + col0] = (t0 ? c7.x : c3.x) * i0;
        LwB[row1 * LPAD +  0 + col1] = (t1 ? c4.y : c0.y) * i1;
        LwB[row1 * LPAD + 16 + col1] = (t1 ? c5.y : c1.y) * i1;
        LwB[row1 * LPAD + 32 + col1] = (t1 ? c6.y : c2.y) * i1;
        LwB[row1 * LPAD + 48 + col1] = (t1 ? c7.y : c3.y) * i1;
        LwB[row2 * LPAD +  0 + col2] = (t2 ? c4.z : c0.z) * i2;
        LwB[row2 * LPAD + 16 + col2] = (t2 ? c5.z : c1.z) * i2;
        LwB[row2 * LPAD + 32 + col2] = (t2 ? c6.z : c2.z) * i2;
        LwB[row2 * LPAD + 48 + col2] = (t2 ? c7.z : c3.z) * i2;
        LwB[row3 * LPAD +  0 + col3] = (t3 ? c4.w : c0.w) * i3;
        LwB[row3 * LPAD + 16 + col3] = (t3 ? c5.w : c1.w) * i3;
        LwB[row3 * LPAD + 32 + col3] = (t3 ? c6.w : c2.w) * i3;
        LwB[row3 * LPAD + 48 + col3] = (t3 ? c7.w : c3.w) * i3;

        if (r == 0) {   // rows {row0..row3} per g partition 0..15 -> full cover
            probOut[(size_t)(ubase + row0) * NSITES + site] = (float)s0;
            probOut[(size_t)(ubase + row1) * NSITES + site] = (float)s1;
            probOut[(size_t)(ubase + row2) * NSITES + site] = (float)s2;
            probOut[(size_t)(ubase + row3) * NSITES + site] = (float)s3;
            *(float2*)(out + (size_t)(ubase + row0) * 128 + site * 2) = make_float2(t0 ? 1.f : 0.f, t0 ? 0.f : 1.f);
            *(float2*)(out + (size_t)(ubase + row1) * 128 + site * 2) = make_float2(t1 ? 1.f : 0.f, t1 ? 0.f : 1.f);
            *(float2*)(out + (size_t)(ubase + row2) * 128 + site * 2) = make_float2(t2 ? 1.f : 0.f, t2 ? 0.f : 1.f);
            *(float2*)(out + (size_t)(ubase + row3) * 128 + site * 2) = make_float2(t3 ? 1.f : 0.f, t3 ? 0.f : 1.f);
        }
    }
}

extern "C" void kernel_launch(void* const* d_in, const int* in_sizes, int n_in,
                              void* d_out, int out_size, void* d_ws, size_t ws_size,
                              hipStream_t stream)
{
    const float* W = (const float*)d_in[0];   // [64,64,2,64] f32
    const float* u = (const float*)d_in[1];   // [32768,64] f32
    float* out = (float*)d_out;               // s_hat [B,64,2] then prob [B,64]
    double* A8 = (double*)d_ws;               // isometrized A, f64, 4 MiB

    hipLaunchKernelGGL(qr_site_kernel, dim3(NSITES), dim3(512), 0, stream, W, A8);
    hipLaunchKernelGGL(sample_kernel, dim3(512), dim3(256), 0, stream, A8, u, out);
}

// Round 17
// 755.305 us; speedup vs baseline: 1.7969x; 1.7969x over previous
//
#include <hip/hip_runtime.h>

#define NSITES 64
#define CHI 64
#define BATCH 32768
#define LPAD 66          // L row stride in doubles

typedef double d4 __attribute__((ext_vector_type(4)));

// 32 cycles of guaranteed spacing between MFMA result writes and VALU reads,
// pinned so the compiler cannot move register-only MFMAs across (rule #18).
#define MFMA_HAZARD_FENCE() do {                                    \
    __builtin_amdgcn_sched_barrier(0);                              \
    asm volatile("s_nop 7\n\ts_nop 7\n\ts_nop 7\n\ts_nop 7" :::);   \
    __builtin_amdgcn_sched_barrier(0);                              \
} while (0)

// ============================================================================
// Kernel 1: per-site Householder QR (LAPACK dgeqrf/dorgqr convention), f64.
// Round-14 version (passing): 2-barrier divergence-free factor phase,
// deferred col-k scaling, zero-barrier Q-phase via Vt transpose.
// ============================================================================
__global__ __launch_bounds__(512) void qr_site_kernel(
    const float* __restrict__ W, double* __restrict__ A8)
{
    __shared__ double M[128][65];
    __shared__ double wpart[8][64];
    __shared__ double tauS[64];
    __shared__ double scS[64];
    __shared__ double redS2[8];
    __shared__ double Vt[64][136];

    const int i   = blockIdx.x;
    const int tid = threadIdx.x;

    for (int idx = tid; idx < 8192; idx += 512) {
        int l = idx >> 7, sr = idx & 127;
        M[sr][l] = (double)W[i * 8192 + idx];
    }

    const int jf = tid & 63;              // lane = column
    const int gf = tid >> 6;              // wave = row group (rows gf*16..+15)
    const int r0 = gf * 16;
    __syncthreads();

    for (int k = 0; k < 64; ++k) {
        // ---- phase A ----
        double ureg[16];
        #pragma unroll
        for (int m = 0; m < 16; ++m) {
            int rr = r0 + m;
            ureg[m] = (rr > k) ? M[rr][k] : 0.0;   // wave-broadcast reads
        }
        double np = 0.0;                  // group norm partial (all lanes, uniform)
        #pragma unroll
        for (int m = 0; m < 16; ++m) np = fma(ureg[m], ureg[m], np);
        if (jf == 0) redS2[gf] = np;
        if (jf > k) {                     // GEMV on unscaled column
            double part = 0.0;
            #pragma unroll 4
            for (int m = 0; m < 16; ++m)
                part = fma(ureg[m], M[r0 + m][jf], part);
            wpart[gf][jf] = part;
        }
        __syncthreads();                  // barrier 1

        // ---- phase B ----
        const double v2 = ((redS2[0] + redS2[1]) + (redS2[2] + redS2[3]))
                        + ((redS2[4] + redS2[5]) + (redS2[6] + redS2[7]));
        const double alpha = M[k][k];
        double beta, tk;
        if (v2 == 0.0) { beta = alpha; tk = 0.0; }
        else {
            double nrm = sqrt(alpha * alpha + v2);
            beta = (alpha >= 0.0) ? -nrm : nrm;   // LAPACK sign convention
            tk   = (beta - alpha) / beta;
        }
        const double uk   = alpha - beta;
        const double sc   = (tk != 0.0) ? (1.0 / uk) : 0.0;
        const double tau2 = (tk != 0.0) ? (tk / (uk * uk)) : 0.0;
        if (tid == 0) { tauS[k] = tk; scS[k] = sc; }
        if (jf > k) {
            const double xk = M[k][jf];   // row-k term (col k never scaled here)
            double wsum = ((wpart[0][jf] + wpart[1][jf]) + (wpart[2][jf] + wpart[3][jf]))
                        + ((wpart[4][jf] + wpart[5][jf]) + (wpart[6][jf] + wpart[7][jf]));
            const double wj = tau2 * fma(uk, xk, wsum);
            #pragma unroll 4
            for (int m = 0; m < 16; ++m) {
                int rr = r0 + m;
                M[rr][jf] = fma(-ureg[m], wj, M[rr][jf]);  // rows<=k: -0*wj, benign
            }
        }
        __syncthreads();                  // barrier 2
    }

    // one-time transpose of v's into Vt, applying the deferred scale
    for (int idx = tid; idx < 8192; idx += 512) {
        int rr = idx & 127, k = idx >> 7;
        double val = (rr > k) ? M[rr][k] * scS[k] : ((rr == k) ? 1.0 : 0.0);
        Vt[k][rr + (rr >> 4)] = val;
    }
    __syncthreads();

    // Q = H_0 ... H_63 applied to [I;0], reverse order — ZERO barriers
    const int jq = tid >> 3;
    const int qq = tid & 7;
    double E[16];
    #pragma unroll
    for (int m = 0; m < 16; ++m) E[m] = ((qq * 16 + m) == jq) ? 1.0 : 0.0;

    for (int k = 63; k >= 0; --k) {
        const double tkk = tauS[k];
        double part = 0.0;
        #pragma unroll
        for (int m = 0; m < 16; ++m) {
            int rr = qq * 16 + m;
            part = fma(Vt[k][rr + qq], E[m], part);
        }
        part += __shfl_xor(part, 1, 64);
        part += __shfl_xor(part, 2, 64);
        part += __shfl_xor(part, 4, 64);
        const double wj = tkk * part;
        #pragma unroll
        for (int m = 0; m < 16; ++m) {
            int rr = qq * 16 + m;
            E[m] = fma(-Vt[k][rr + qq], wj, E[m]);
        }
    }

    double* dst = A8 + (size_t)i * 8192 + jq * 128 + qq * 16;
    #pragma unroll
    for (int m = 0; m < 16; ++m) dst[m] = E[m];
}

// ============================================================================
// Kernel 2: sampling via f64 MFMA GEMM per site — ROUND-13/14 version VERBATIM
// (best measured: 653 us, MfmaUtil 73.8%, replay-stable). Zero-serial staging:
//   issue nxH0 | MFMA kk0..7 (H0) | BAR_A | ds_write H0 + issue nxH1 |
//   MFMA kk8..15 (H1) | fence | epilogue+L+outputs | BAR_B | ds_write H1
// r15 (BAR_B moved) and r16 (barrier-free L2-direct) both regressed; this
// schedule is the converged structure.
// ============================================================================
#define MFMA_ROW(bp, a)                                                   \
    c0 = __builtin_amdgcn_mfma_f64_16x16x4f64((a), (bp)[  0], c0, 0,0,0); \
    c1 = __builtin_amdgcn_mfma_f64_16x16x4f64((a), (bp)[ 16], c1, 0,0,0); \
    c2 = __builtin_amdgcn_mfma_f64_16x16x4f64((a), (bp)[ 32], c2, 0,0,0); \
    c3 = __builtin_amdgcn_mfma_f64_16x16x4f64((a), (bp)[ 48], c3, 0,0,0); \
    c4 = __builtin_amdgcn_mfma_f64_16x16x4f64((a), (bp)[ 64], c4, 0,0,0); \
    c5 = __builtin_amdgcn_mfma_f64_16x16x4f64((a), (bp)[ 80], c5, 0,0,0); \
    c6 = __builtin_amdgcn_mfma_f64_16x16x4f64((a), (bp)[ 96], c6, 0,0,0); \
    c7 = __builtin_amdgcn_mfma_f64_16x16x4f64((a), (bp)[112], c7, 0,0,0);

__global__ __launch_bounds__(512, 2) void sample_kernel(
    const double* __restrict__ A8, const float* __restrict__ u,
    float* __restrict__ out)
{
    __shared__ __align__(16) double As[8192];        // A_i: [j=64][sr=128], 64 KiB
    __shared__ double Lsm[128 * LPAD];               // L: [b=128][j=64 + pad], 66 KiB

    const int tid  = threadIdx.x;
    const int w    = tid >> 6;            // wave 0..7
    const int lane = tid & 63;
    const int g    = lane >> 4;           // 0..3
    const int r    = lane & 15;           // 0..15
    const int ubase = blockIdx.x * 128 + 16 * w;   // strip's first global batch

    // ---- layout probe (register-only, once) ----
    d4 zp = {0.0, 0.0, 0.0, 0.0};
    const d4 rowP = __builtin_amdgcn_mfma_f64_16x16x4f64((g == 0) ? (double)r : 0.0, 1.0, zp, 0, 0, 0);
    const d4 colP = __builtin_amdgcn_mfma_f64_16x16x4f64((g == 0) ? 1.0 : 0.0, (double)r, zp, 0, 0, 0);
    MFMA_HAZARD_FENCE();
    const int row0 = (int)(rowP.x + 0.5), row1 = (int)(rowP.y + 0.5);
    const int row2 = (int)(rowP.z + 0.5), row3 = (int)(rowP.w + 0.5);
    const int col0 = (int)(colP.x + 0.5), col1 = (int)(colP.y + 0.5);
    const int col2 = (int)(colP.z + 0.5), col3 = (int)(colP.w + 0.5);

    // init L = e_0: lane (g,r) initializes row 16w+r, cols g, g+4, ...
    for (int j = g; j < 64; j += 4)
        Lsm[(16 * w + r) * LPAD + j] = (j == 0) ? 1.0 : 0.0;

    {   // stage site 0 (full)
        const double2* s2 = (const double2*)A8;
        double2* a2 = (double2*)As;
        #pragma unroll
        for (int q = 0; q < 8; ++q) a2[q * 512 + tid] = s2[q * 512 + tid];
    }
    __syncthreads();

    float* probOut = out + (size_t)BATCH * (NSITES * 2);

    for (int site = 0; site < NSITES; ++site) {
        // u values for this lane's (probed) batch rows
        const float u0 = u[(size_t)(ubase + row0) * NSITES + site];
        const float u1 = u[(size_t)(ubase + row1) * NSITES + site];
        const float u2 = u[(size_t)(ubase + row2) * NSITES + site];
        const float u3 = u[(size_t)(ubase + row3) * NSITES + site];

        // issue next-site H0 loads (arrive under first MFMA half)
        double2 st0, st1, st2, st3;
        if (site < NSITES - 1) {
            const double2* nx = (const double2*)(A8 + (size_t)(site + 1) * 8192);
            st0 = nx[0 * 512 + tid]; st1 = nx[1 * 512 + tid];
            st2 = nx[2 * 512 + tid]; st3 = nx[3 * 512 + tid];
        }

        d4 c0 = {0.0, 0.0, 0.0, 0.0}, c1 = c0, c2 = c0, c3 = c0;
        d4 c4 = c0, c5 = c0, c6 = c0, c7 = c0;

        const double* Lp = Lsm + (16 * w + r) * LPAD + g;   // A-op: L[16w+r][g+4kk]
        const double* Ap = As + g * 128 + r;                // B-op: A[g+4kk][16t+r]

        // ---- first half: kk 0..7 (reads As rows 0..31 = H0) ----
        #pragma unroll
        for (int kk = 0; kk < 8; ++kk) {
            const double a = Lp[4 * kk];
            const double* bp = Ap + kk * 512;
            MFMA_ROW(bp, a)
        }

        __syncthreads();                 // BAR_A: all H0 reads done

        // overwrite H0 + issue H1 loads; both overlap the second MFMA half
        double2 st4, st5, st6, st7;
        if (site < NSITES - 1) {
            double2* a2 = (double2*)As;
            a2[0 * 512 + tid] = st0; a2[1 * 512 + tid] = st1;
            a2[2 * 512 + tid] = st2; a2[3 * 512 + tid] = st3;
            const double2* nx = (const double2*)(A8 + (size_t)(site + 1) * 8192);
            st4 = nx[4 * 512 + tid]; st5 = nx[5 * 512 + tid];
            st6 = nx[6 * 512 + tid]; st7 = nx[7 * 512 + tid];
        }

        // ---- second half: kk 8..15 (reads As rows 32..63 = H1) ----
        #pragma unroll
        for (int kk = 8; kk < 16; ++kk) {
            const double a = Lp[4 * kk];
            const double* bp = Ap + kk * 512;
            MFMA_ROW(bp, a)
        }
        MFMA_HAZARD_FENCE();             // settle all c-reg writes before VALU reads

        // p0 per row: tiles 0..3 are the s=0 half (col-permutation-invariant);
        // xor-butterfly over the 16-lane group (row map is r-independent).
        double P0 = fma(c3.x, c3.x, fma(c2.x, c2.x, fma(c1.x, c1.x, c0.x * c0.x)));
        double P1 = fma(c3.y, c3.y, fma(c2.y, c2.y, fma(c1.y, c1.y, c0.y * c0.y)));
        double P2 = fma(c3.z, c3.z, fma(c2.z, c2.z, fma(c1.z, c1.z, c0.z * c0.z)));
        double P3 = fma(c3.w, c3.w, fma(c2.w, c2.w, fma(c1.w, c1.w, c0.w * c0.w)));
        #pragma unroll
        for (int m = 1; m <= 8; m <<= 1) {
            P0 += __shfl_xor(P0, m, 64);
            P1 += __shfl_xor(P1, m, 64);
            P2 += __shfl_xor(P2, m, 64);
            P3 += __shfl_xor(P3, m, 64);
        }

        const bool t0 = ((double)u0 >= P0);
        const bool t1 = ((double)u1 >= P1);
        const bool t2 = ((double)u2 >= P2);
        const bool t3 = ((double)u3 >= P3);
        const double s0 = t0 ? (1.0 - P0) : P0;   // p0+p1==1 by isometry
        const double s1 = t1 ? (1.0 - P1) : P1;
        const double s2 = t2 ? (1.0 - P2) : P2;
        const double s3 = t3 ? (1.0 - P3) : P3;
        const double i0 = rsqrt(s0);              // ~1 ulp; perturbs L ~1e-15 rel
        const double i1 = rsqrt(s1);
        const double i2 = rsqrt(s2);
        const double i3 = rsqrt(s3);

        // chosen T -> new L rows at probed (row,col); strip-private (no barrier)
        double* LwB = Lsm + (16 * w) * LPAD;
        LwB[row0 * LPAD +  0 + col0] = (t0 ? c4.x : c0.x) * i0;
        LwB[row0 * LPAD + 16 + col0] = (t0 ? c5.x : c1.x) * i0;
        LwB[row0 * LPAD + 32 + col0] = (t0 ? c6.x : c2.x) * i0;
        LwB[row0 * LPAD + 48 + col0] = (t0 ? c7.x : c3.x) * i0;
        LwB[row1 * LPAD +  0 + col1] = (t1 ? c4.y : c0.y) * i1;
        LwB[row1 * LPAD + 16 + col1] = (t1 ? c5.y : c1.y) * i1;
        LwB[row1 * LPAD + 32 + col1] = (t1 ? c6.y : c2.y) * i1;
        LwB[row1 * LPAD + 48 + col1] = (t1 ? c7.y : c3.y) * i1;
        LwB[row2 * LPAD +  0 + col2] = (t2 ? c4.z : c0.z) * i2;
        LwB[row2 * LPAD + 16 + col2] = (t2 ? c5.z : c1.z) * i2;
        LwB[row2 * LPAD + 32 + col2] = (t2 ? c6.z : c2.z) * i2;
        LwB[row2 * LPAD + 48 + col2] = (t2 ? c7.z : c3.z) * i2;
        LwB[row3 * LPAD +  0 + col3] = (t3 ? c4.w : c0.w) * i3;
        LwB[row3 * LPAD + 16 + col3] = (t3 ? c5.w : c1.w) * i3;
        LwB[row3 * LPAD + 32 + col3] = (t3 ? c6.w : c2.w) * i3;
        LwB[row3 * LPAD + 48 + col3] = (t3 ? c7.w : c3.w) * i3;

        if (r == 0) {   // rows {row0..row3} per g partition 0..15 -> full cover
            probOut[(size_t)(ubase + row0) * NSITES + site] = (float)s0;
            probOut[(size_t)(ubase + row1) * NSITES + site] = (float)s1;
            probOut[(size_t)(ubase + row2) * NSITES + site] = (float)s2;
            probOut[(size_t)(ubase + row3) * NSITES + site] = (float)s3;
            *(float2*)(out + (size_t)(ubase + row0) * 128 + site * 2) = make_float2(t0 ? 1.f : 0.f, t0 ? 0.f : 1.f);
            *(float2*)(out + (size_t)(ubase + row1) * 128 + site * 2) = make_float2(t1 ? 1.f : 0.f, t1 ? 0.f : 1.f);
            *(float2*)(out + (size_t)(ubase + row2) * 128 + site * 2) = make_float2(t2 ? 1.f : 0.f, t2 ? 0.f : 1.f);
            *(float2*)(out + (size_t)(ubase + row3) * 128 + site * 2) = make_float2(t3 ? 1.f : 0.f, t3 ? 0.f : 1.f);
        }

        __syncthreads();                 // BAR_B: all H1 reads done; H0 staged

        // write H1 (overlaps next site's u-loads/glb-issue/H0 MFMAs)
        if (site < NSITES - 1) {
            double2* a2 = (double2*)As;
            a2[4 * 512 + tid] = st4; a2[5 * 512 + tid] = st5;
            a2[6 * 512 + tid] = st6; a2[7 * 512 + tid] = st7;
        }
    }
}

extern "C" void kernel_launch(void* const* d_in, const int* in_sizes, int n_in,
                              void* d_out, int out_size, void* d_ws, size_t ws_size,
                              hipStream_t stream)
{
    const float* W = (const float*)d_in[0];   // [64,64,2,64] f32
    const float* u = (const float*)d_in[1];   // [32768,64] f32
    float* out = (float*)d_out;               // s_hat [B,64,2] then prob [B,64]
    double* A8 = (double*)d_ws;               // isometrized A, f64, 4 MiB

    hipLaunchKernelGGL(qr_site_kernel, dim3(NSITES), dim3(512), 0, stream, W, A8);
    hipLaunchKernelGGL(sample_kernel, dim3(256), dim3(512), 0, stream, A8, u, out);
}